// Round 1
// baseline (2078.815 us; speedup 1.0000x reference)
//
#include <hip/hip_runtime.h>
#include <hip/hip_bf16.h>

#define NN 100000
#define EPR 1600000
#define FIN 256
#define FOUT 64

// ---------------- degree counting ----------------
__global__ void deg_kernel(const int* __restrict__ src, const int* __restrict__ dst,
                           unsigned* __restrict__ deg_s, unsigned* __restrict__ deg_d, int nE) {
    int i = blockIdx.x * blockDim.x + threadIdx.x;
    int stride = gridDim.x * blockDim.x;
    for (int e = i; e < nE; e += stride) {
        atomicAdd(&deg_s[src[e]], 1u);
        atomicAdd(&deg_d[dst[e]], 1u);
    }
}

// ---------------- degree -> rsqrt norm ----------------
__global__ void norm_kernel(const unsigned* __restrict__ deg_s, const unsigned* __restrict__ deg_d,
                            float* __restrict__ ns, float* __restrict__ nd, int n) {
    int i = blockIdx.x * blockDim.x + threadIdx.x;
    if (i < n) {
        unsigned a = deg_s[i]; if (a < 1u) a = 1u;
        unsigned b = deg_d[i]; if (b < 1u) b = 1u;
        ns[i] = rsqrtf((float)a);
        nd[i] = rsqrtf((float)b);
    }
}

// ---------------- fp32 GEMM: h[N,64] = x[N,256] @ w[256,64] ----------------
#define BM 128
#define BK 32
__global__ __launch_bounds__(256) void gemm_kernel(const float* __restrict__ x,
                                                   const float* __restrict__ w,
                                                   float* __restrict__ h) {
    __shared__ float xs[BK][BM];     // transposed x tile: xs[k][m]
    __shared__ float wsh[BK][FOUT];  // w tile
    int tid = threadIdx.x;
    int m0 = blockIdx.x * BM;
    int tc = tid & 7;        // 8 col groups of 8
    int tr = tid >> 3;       // 32 row groups of 4
    float acc[4][8];
    #pragma unroll
    for (int i = 0; i < 4; i++)
        #pragma unroll
        for (int j = 0; j < 8; j++) acc[i][j] = 0.f;

    for (int k0 = 0; k0 < FIN; k0 += BK) {
        // x tile: 128x32 floats = 1024 float4, 4 per thread
        #pragma unroll
        for (int t = 0; t < 4; ++t) {
            int f = tid * 4 + t;        // 0..1023
            int row = f >> 3;           // 0..127
            int kp = (f & 7) << 2;      // 0..28 step 4
            int gr = m0 + row;
            const float4 v = *(const float4*)&x[(size_t)(gr < NN ? gr : 0) * FIN + k0 + kp];
            xs[kp + 0][row] = v.x;
            xs[kp + 1][row] = v.y;
            xs[kp + 2][row] = v.z;
            xs[kp + 3][row] = v.w;
        }
        // w tile: 32x64 = 512 float4, 2 per thread
        #pragma unroll
        for (int t = 0; t < 2; ++t) {
            int f = tid * 2 + t;        // 0..511
            int kk = f >> 4;            // 0..31
            int c = (f & 15) << 2;      // 0..60 step 4
            *(float4*)&wsh[kk][c] = *(const float4*)&w[(size_t)(k0 + kk) * FOUT + c];
        }
        __syncthreads();
        #pragma unroll
        for (int k = 0; k < BK; ++k) {
            float4 xv = *(const float4*)&xs[k][tr * 4];
            float4 w0 = *(const float4*)&wsh[k][tc * 8];
            float4 w1 = *(const float4*)&wsh[k][tc * 8 + 4];
            float xa[4] = {xv.x, xv.y, xv.z, xv.w};
            float wb[8] = {w0.x, w0.y, w0.z, w0.w, w1.x, w1.y, w1.z, w1.w};
            #pragma unroll
            for (int i = 0; i < 4; i++)
                #pragma unroll
                for (int j = 0; j < 8; j++)
                    acc[i][j] = fmaf(xa[i], wb[j], acc[i][j]);
        }
        __syncthreads();
    }
    #pragma unroll
    for (int i = 0; i < 4; i++) {
        int gr = m0 + tr * 4 + i;
        if (gr < NN) {
            float4 o0 = {acc[i][0], acc[i][1], acc[i][2], acc[i][3]};
            float4 o1 = {acc[i][4], acc[i][5], acc[i][6], acc[i][7]};
            *(float4*)&h[(size_t)gr * FOUT + tc * 8] = o0;
            *(float4*)&h[(size_t)gr * FOUT + tc * 8 + 4] = o1;
        }
    }
}

// ---------------- edge scatter: wave per edge ----------------
__global__ void edge_kernel(const int* __restrict__ src, const int* __restrict__ dst,
                            const float* __restrict__ h, const float* __restrict__ ns,
                            const float* __restrict__ nd, float* __restrict__ acc, int nE) {
    int gtid = blockIdx.x * blockDim.x + threadIdx.x;
    int wave = gtid >> 6;
    int lane = threadIdx.x & 63;
    int nw = (gridDim.x * blockDim.x) >> 6;
    for (int e = wave; e < nE; e += nw) {
        int s = src[e];
        int d = dst[e];
        float scale = ns[s] * nd[d];   // wave-uniform
        float v = h[(size_t)s * FOUT + lane] * scale;
        atomicAdd(&acc[(size_t)d * FOUT + lane], v);
    }
}

// ---------------- tanh epilogue (in place on d_out) ----------------
__global__ void tanh_kernel(float* __restrict__ out, int n4) {
    int i = blockIdx.x * blockDim.x + threadIdx.x;
    int stride = gridDim.x * blockDim.x;
    for (int j = i; j < n4; j += stride) {
        float4 v = ((float4*)out)[j];
        v.x = tanhf(v.x);
        v.y = tanhf(v.y);
        v.z = tanhf(v.z);
        v.w = tanhf(v.w);
        ((float4*)out)[j] = v;
    }
}

extern "C" void kernel_launch(void* const* d_in, const int* in_sizes, int n_in,
                              void* d_out, int out_size, void* d_ws, size_t ws_size,
                              hipStream_t stream) {
    const float* x = (const float*)d_in[0];
    const float* W = (const float*)d_in[1];
    const int* ei = (const int*)d_in[2];
    float* out = (float*)d_out;

    char* ws = (char*)d_ws;
    float* h = (float*)ws;                                        // N*64 f32 = 25.6 MB
    unsigned* deg = (unsigned*)(ws + (size_t)NN * FOUT * 4);      // 2*N u32
    float* norms = (float*)(ws + (size_t)NN * FOUT * 4 + (size_t)2 * NN * 4); // 2*N f32
    unsigned* deg_s = deg;
    unsigned* deg_d = deg + NN;
    float* ns = norms;
    float* nd = norms + NN;

    // zero the output accumulator (poisoned / stale between replays)
    hipMemsetAsync(d_out, 0, (size_t)out_size * sizeof(float), stream);

    for (int r = 0; r < 4; ++r) {
        const int* src = ei + (size_t)r * 2 * EPR;
        const int* dst = src + EPR;
        const float* w = W + (size_t)r * FIN * FOUT;

        hipMemsetAsync(deg, 0, (size_t)2 * NN * sizeof(unsigned), stream);
        deg_kernel<<<2048, 256, 0, stream>>>(src, dst, deg_s, deg_d, EPR);
        norm_kernel<<<(NN + 255) / 256, 256, 0, stream>>>(deg_s, deg_d, ns, nd, NN);
        gemm_kernel<<<(NN + BM - 1) / BM, 256, 0, stream>>>(x, w, h);
        edge_kernel<<<4096, 256, 0, stream>>>(src, dst, h, ns, nd, out, EPR);
    }
    tanh_kernel<<<2048, 256, 0, stream>>>(out, out_size / 4);
}

// Round 2
// 1680.751 us; speedup vs baseline: 1.2368x; 1.2368x over previous
//
#include <hip/hip_runtime.h>
#include <hip/hip_bf16.h>

#define NN 100000
#define EPR 1600000
#define FIN 256
#define FOUT 64
#define NSCAN_BLOCKS ((NN + 1023) / 1024)   // 98

// ---------------- degree counting ----------------
__global__ void deg_kernel(const int* __restrict__ src, const int* __restrict__ dst,
                           unsigned* __restrict__ deg_s, unsigned* __restrict__ deg_d, int nE) {
    int i = blockIdx.x * blockDim.x + threadIdx.x;
    int stride = gridDim.x * blockDim.x;
    for (int e = i; e < nE; e += stride) {
        atomicAdd(&deg_s[src[e]], 1u);
        atomicAdd(&deg_d[dst[e]], 1u);
    }
}

// ---------------- degree -> rsqrt norm ----------------
__global__ void norm_kernel(const unsigned* __restrict__ deg_s, const unsigned* __restrict__ deg_d,
                            float* __restrict__ ns, float* __restrict__ nd, int n) {
    int i = blockIdx.x * blockDim.x + threadIdx.x;
    if (i < n) {
        unsigned a = deg_s[i]; if (a < 1u) a = 1u;
        unsigned b = deg_d[i]; if (b < 1u) b = 1u;
        ns[i] = rsqrtf((float)a);
        nd[i] = rsqrtf((float)b);
    }
}

// ---------------- fp32 GEMM: hs[N,64] = (x[N,256] @ w[256,64]) * ns[row] ----------------
#define BM 128
#define BK 32
__global__ __launch_bounds__(256) void gemm_kernel(const float* __restrict__ x,
                                                   const float* __restrict__ w,
                                                   float* __restrict__ hs,
                                                   const float* __restrict__ ns) {
    __shared__ float xs[BK][BM];     // transposed x tile: xs[k][m]
    __shared__ float wsh[BK][FOUT];  // w tile
    int tid = threadIdx.x;
    int m0 = blockIdx.x * BM;
    int tc = tid & 7;        // 8 col groups of 8
    int tr = tid >> 3;       // 32 row groups of 4
    float acc[4][8];
    #pragma unroll
    for (int i = 0; i < 4; i++)
        #pragma unroll
        for (int j = 0; j < 8; j++) acc[i][j] = 0.f;

    for (int k0 = 0; k0 < FIN; k0 += BK) {
        #pragma unroll
        for (int t = 0; t < 4; ++t) {
            int f = tid * 4 + t;
            int row = f >> 3;
            int kp = (f & 7) << 2;
            int gr = m0 + row;
            const float4 v = *(const float4*)&x[(size_t)(gr < NN ? gr : 0) * FIN + k0 + kp];
            xs[kp + 0][row] = v.x;
            xs[kp + 1][row] = v.y;
            xs[kp + 2][row] = v.z;
            xs[kp + 3][row] = v.w;
        }
        #pragma unroll
        for (int t = 0; t < 2; ++t) {
            int f = tid * 2 + t;
            int kk = f >> 4;
            int c = (f & 15) << 2;
            *(float4*)&wsh[kk][c] = *(const float4*)&w[(size_t)(k0 + kk) * FOUT + c];
        }
        __syncthreads();
        #pragma unroll
        for (int k = 0; k < BK; ++k) {
            float4 xv = *(const float4*)&xs[k][tr * 4];
            float4 w0 = *(const float4*)&wsh[k][tc * 8];
            float4 w1 = *(const float4*)&wsh[k][tc * 8 + 4];
            float xa[4] = {xv.x, xv.y, xv.z, xv.w};
            float wb[8] = {w0.x, w0.y, w0.z, w0.w, w1.x, w1.y, w1.z, w1.w};
            #pragma unroll
            for (int i = 0; i < 4; i++)
                #pragma unroll
                for (int j = 0; j < 8; j++)
                    acc[i][j] = fmaf(xa[i], wb[j], acc[i][j]);
        }
        __syncthreads();
    }
    #pragma unroll
    for (int i = 0; i < 4; i++) {
        int gr = m0 + tr * 4 + i;
        if (gr < NN) {
            float sc = ns[gr];
            float4 o0 = {acc[i][0] * sc, acc[i][1] * sc, acc[i][2] * sc, acc[i][3] * sc};
            float4 o1 = {acc[i][4] * sc, acc[i][5] * sc, acc[i][6] * sc, acc[i][7] * sc};
            *(float4*)&hs[(size_t)gr * FOUT + tc * 8] = o0;
            *(float4*)&hs[(size_t)gr * FOUT + tc * 8 + 4] = o1;
        }
    }
}

// ---------------- prefix scan (exclusive) of in-degrees ----------------
__global__ void scan_sum_kernel(const unsigned* __restrict__ cnt, unsigned* __restrict__ bsum) {
    __shared__ unsigned sdata[256];
    int b = blockIdx.x, t = threadIdx.x;
    int base = b * 1024 + t * 4;
    unsigned s = 0;
    #pragma unroll
    for (int k = 0; k < 4; k++) { int i = base + k; s += (i < NN) ? cnt[i] : 0u; }
    sdata[t] = s; __syncthreads();
    for (int off = 128; off > 0; off >>= 1) {
        if (t < off) sdata[t] += sdata[t + off];
        __syncthreads();
    }
    if (t == 0) bsum[b] = sdata[0];
}

__global__ void scan_carry_kernel(const unsigned* __restrict__ bsum, unsigned* __restrict__ boff,
                                  unsigned* __restrict__ off_last) {
    unsigned c = 0;
    for (int i = 0; i < NSCAN_BLOCKS; i++) { boff[i] = c; c += bsum[i]; }
    *off_last = c;   // off[NN] == EPR
}

__global__ void scan_off_kernel(const unsigned* __restrict__ cnt, const unsigned* __restrict__ boff,
                                unsigned* __restrict__ off, unsigned* __restrict__ cur) {
    __shared__ unsigned sdata[256];
    int b = blockIdx.x, t = threadIdx.x;
    int base = b * 1024 + t * 4;
    unsigned v[4]; unsigned s = 0;
    #pragma unroll
    for (int k = 0; k < 4; k++) { int i = base + k; v[k] = (i < NN) ? cnt[i] : 0u; s += v[k]; }
    sdata[t] = s; __syncthreads();
    for (int o = 1; o < 256; o <<= 1) {
        unsigned add = (t >= o) ? sdata[t - o] : 0u;
        __syncthreads();
        sdata[t] += add;
        __syncthreads();
    }
    unsigned texcl = (t > 0) ? sdata[t - 1] : 0u;
    unsigned run = boff[b] + texcl;
    #pragma unroll
    for (int k = 0; k < 4; k++) {
        int i = base + k;
        if (i < NN) { off[i] = run; cur[i] = run; run += v[k]; }
    }
}

// ---------------- scatter edges into dst-sorted order ----------------
__global__ void scatter_kernel(const int* __restrict__ src, const int* __restrict__ dst,
                               unsigned* __restrict__ cur, int* __restrict__ ssrc, int nE) {
    int i = blockIdx.x * blockDim.x + threadIdx.x;
    int stride = gridDim.x * blockDim.x;
    for (int e = i; e < nE; e += stride) {
        int d = dst[e];
        unsigned p = atomicAdd(&cur[d], 1u);
        ssrc[p] = src[e];
    }
}

// ---------------- owner-wave aggregation: one wave per dst node ----------------
template<bool LAST>
__global__ __launch_bounds__(256) void agg_kernel(const int* __restrict__ ssrc,
                                                  const unsigned* __restrict__ off,
                                                  const float* __restrict__ hs,
                                                  const float* __restrict__ nd,
                                                  float* __restrict__ out) {
    int node = blockIdx.x * 4 + (threadIdx.x >> 6);
    int lane = threadIdx.x & 63;
    if (node >= NN) return;
    unsigned b = off[node], e = off[node + 1];
    int cnt = (int)(e - b);
    float acc = 0.f;
    for (int base = 0; base < cnt; base += 64) {
        int m = cnt - base; if (m > 64) m = 64;
        int sl = (base + lane < cnt) ? ssrc[b + base + lane] : 0;
        for (int j = 0; j < m; j++) {
            int s = __shfl(sl, j);
            acc += hs[(size_t)s * FOUT + lane];
        }
    }
    size_t oi = (size_t)node * FOUT + lane;
    float r = out[oi] + acc * nd[node];
    out[oi] = LAST ? tanhf(r) : r;
}

// ---------------- fallback (round-1 style) edge scatter with atomics ----------------
__global__ void edge_kernel_fb(const int* __restrict__ src, const int* __restrict__ dst,
                               const float* __restrict__ hs, const float* __restrict__ nd,
                               float* __restrict__ acc, int nE) {
    int gtid = blockIdx.x * blockDim.x + threadIdx.x;
    int wave = gtid >> 6;
    int lane = threadIdx.x & 63;
    int nw = (gridDim.x * blockDim.x) >> 6;
    for (int e = wave; e < nE; e += nw) {
        int s = src[e];
        int d = dst[e];
        float v = hs[(size_t)s * FOUT + lane] * nd[d];
        atomicAdd(&acc[(size_t)d * FOUT + lane], v);
    }
}

__global__ void tanh_kernel(float* __restrict__ out, int n4) {
    int i = blockIdx.x * blockDim.x + threadIdx.x;
    int stride = gridDim.x * blockDim.x;
    for (int j = i; j < n4; j += stride) {
        float4 v = ((float4*)out)[j];
        v.x = tanhf(v.x); v.y = tanhf(v.y); v.z = tanhf(v.z); v.w = tanhf(v.w);
        ((float4*)out)[j] = v;
    }
}

extern "C" void kernel_launch(void* const* d_in, const int* in_sizes, int n_in,
                              void* d_out, int out_size, void* d_ws, size_t ws_size,
                              hipStream_t stream) {
    const float* x = (const float*)d_in[0];
    const float* W = (const float*)d_in[1];
    const int* ei = (const int*)d_in[2];
    float* out = (float*)d_out;

    char* ws = (char*)d_ws;
    size_t o = 0;
    float* hs = (float*)(ws + o);        o += (size_t)NN * FOUT * 4;     // 25.6 MB
    float* ns = (float*)(ws + o);        o += (size_t)NN * 4;
    float* nd = (float*)(ws + o);        o += (size_t)NN * 4;
    unsigned* deg_s = (unsigned*)(ws + o); o += (size_t)NN * 4;
    unsigned* deg_d = (unsigned*)(ws + o); o += (size_t)NN * 4;
    unsigned* off = (unsigned*)(ws + o); o += (size_t)(NN + 4) * 4;
    unsigned* cur = (unsigned*)(ws + o); o += (size_t)NN * 4;
    unsigned* bsum = (unsigned*)(ws + o); o += 128 * 4;
    unsigned* boff = (unsigned*)(ws + o); o += 128 * 4;
    int* ssrc = (int*)(ws + o);          o += (size_t)EPR * 4;           // 6.4 MB
    bool fits = (o <= ws_size);

    hipMemsetAsync(d_out, 0, (size_t)out_size * sizeof(float), stream);

    for (int r = 0; r < 4; ++r) {
        const int* src = ei + (size_t)r * 2 * EPR;
        const int* dst = src + EPR;
        const float* w = W + (size_t)r * FIN * FOUT;

        hipMemsetAsync(deg_s, 0, (size_t)2 * NN * sizeof(unsigned), stream);
        deg_kernel<<<2048, 256, 0, stream>>>(src, dst, deg_s, deg_d, EPR);
        norm_kernel<<<(NN + 255) / 256, 256, 0, stream>>>(deg_s, deg_d, ns, nd, NN);
        gemm_kernel<<<(NN + BM - 1) / BM, 256, 0, stream>>>(x, w, hs, ns);

        if (fits) {
            scan_sum_kernel<<<NSCAN_BLOCKS, 256, 0, stream>>>(deg_d, bsum);
            scan_carry_kernel<<<1, 1, 0, stream>>>(bsum, boff, &off[NN]);
            scan_off_kernel<<<NSCAN_BLOCKS, 256, 0, stream>>>(deg_d, boff, off, cur);
            scatter_kernel<<<2048, 256, 0, stream>>>(src, dst, cur, ssrc, EPR);
            if (r == 3)
                agg_kernel<true><<<(NN + 3) / 4, 256, 0, stream>>>(ssrc, off, hs, nd, out);
            else
                agg_kernel<false><<<(NN + 3) / 4, 256, 0, stream>>>(ssrc, off, hs, nd, out);
        } else {
            edge_kernel_fb<<<4096, 256, 0, stream>>>(src, dst, hs, nd, out, EPR);
            if (r == 3) tanh_kernel<<<2048, 256, 0, stream>>>(out, out_size / 4);
        }
    }
}